// Round 10
// baseline (248.238 us; speedup 1.0000x reference)
//
#include <hip/hip_runtime.h>
#include <hip/hip_cooperative_groups.h>
#include <cstddef>

#define XSZ 512
#define YSZ 512
#define NB  4
#define NC  64
#define NP  20000
#define H3 48
#define W3 160
#define H4 24
#define W4 80
#define H5 12
#define W5 40
#define HW3 (H3*W3)
#define HW4 (H4*W4)
#define HW5 (H5*W5)
#define HWO (XSZ*YSZ)

#define GRID2 1024       // cooperative grid: 4 blocks/CU * 256 CU
#define CAP   96         // vec slots per block (2 rows: mean ~39 winners,
                         // max over 1024 blocks ~70; overflow -> phase D)

#define T3_TILES (NB * ((HW3 + 63) / 64))  // 480
#define T4_TILES (NB * ((HW4 + 63) / 64))  // 120
#define T5_TILES (NB * ((HW5 + 63) / 64))  // 32
#define T_TOTAL  (T3_TILES + T4_TILES + T5_TILES)   // 632
#define SCAT_BLOCKS ((NB * NP + 255) / 256)         // 313  (632+313=945 <= 1024)

typedef float f4 __attribute__((ext_vector_type(4)));

// ---------------------------------------------------------------------------
// Bilinear, exact f32 replay of the reference arithmetic. Transposed [H,W,C]
// layout: per-tap wave read = 64 consecutive floats = one 256B segment.
// ---------------------------------------------------------------------------
__device__ __forceinline__ float bilinT(const float* __restrict__ img, int H, int W,
                                        float px, float py, int c) {
    float gx = px * 2.0f - 1.0f;
    float gy = py * 2.0f - 1.0f;
    float x = (gx + 1.0f) * 0.5f * (float)(W - 1);
    float y = (gy + 1.0f) * 0.5f * (float)(H - 1);
    float x0f = floorf(x), y0f = floorf(y);
    float wx1 = x - x0f,   wy1 = y - y0f;
    float wx0 = 1.0f - wx1, wy0 = 1.0f - wy1;
    int x0 = (int)x0f, y0 = (int)y0f;
    float acc = 0.0f;
#pragma unroll
    for (int dy = 0; dy < 2; ++dy) {
#pragma unroll
        for (int dx = 0; dx < 2; ++dx) {
            int xi = x0 + dx, yi = y0 + dy;
            bool valid = (xi >= 0) && (xi <= W - 1) && (yi >= 0) && (yi <= H - 1);
            int xc = min(max(xi, 0), W - 1);
            int yc = min(max(yi, 0), H - 1);
            float w = (dx ? wx1 : wx0) * (dy ? wy1 : wy0);
            float v = img[(size_t)(yc * W + xc) * NC + c];
            acc = fmaf(v, valid ? w : 0.0f, acc);
        }
    }
    return acc;
}

// generic-stride variant for the no-transpose fallback
__device__ __forceinline__ float bilinG(const float* __restrict__ img, int H, int W,
                                        float px, float py, int c, int sChan) {
    float gx = px * 2.0f - 1.0f;
    float gy = py * 2.0f - 1.0f;
    float x = (gx + 1.0f) * 0.5f * (float)(W - 1);
    float y = (gy + 1.0f) * 0.5f * (float)(H - 1);
    float x0f = floorf(x), y0f = floorf(y);
    float wx1 = x - x0f,   wy1 = y - y0f;
    float wx0 = 1.0f - wx1, wy0 = 1.0f - wy1;
    int x0 = (int)x0f, y0 = (int)y0f;
    float acc = 0.0f;
#pragma unroll
    for (int dy = 0; dy < 2; ++dy) {
#pragma unroll
        for (int dx = 0; dx < 2; ++dx) {
            int xi = x0 + dx, yi = y0 + dy;
            bool valid = (xi >= 0) && (xi <= W - 1) && (yi >= 0) && (yi <= H - 1);
            int xc = min(max(xi, 0), W - 1);
            int yc = min(max(yi, 0), H - 1);
            float w = (dx ? wx1 : wx0) * (dy ? wy1 : wy0);
            float v = img[(size_t)(yc * W + xc) + (size_t)c * sChan];
            acc = fmaf(v, valid ? w : 0.0f, acc);
        }
    }
    return acc;
}

// ---------------------------------------------------------------------------
// Single cooperative kernel, 1024 blocks x 256 threads, co-resident (4/CU).
//   phase 0: winner <- -1 (1024 blk * 256 thr * 1 int4 = 4 MiB)
//   grid.sync
//   phase 1: blocks [0,632):  LDS-tiled transpose [B,C,H,W]->[B,H,W,C]
//            blocks [632,945): scatter winner[b][cx][cy] = max p (contains>0)
//            (concurrent -- disjoint block ranges)
//   grid.sync
//   phase 2: fused sample + exactly-once dense write. Block owns (b, x0..x0+1):
//            A: scan 2 winner rows -> slot list;  B: wave per winning cell,
//            3 bilinears (lane=channel) into vec[slot][65];  C: per channel,
//            256 threads write 1024 consecutive floats (4 KB contiguous);
//            D: overflow slots (>CAP; ~never) scattered stores.
// ---------------------------------------------------------------------------
__global__ void __launch_bounds__(256, 4)
k_all(const float* __restrict__ c3, const float* __restrict__ c4,
      const float* __restrict__ c5,
      float* __restrict__ c3t, float* __restrict__ c4t, float* __restrict__ c5t,
      const float* __restrict__ dyn, const float* __restrict__ pnts,
      const int* __restrict__ coors, const int* __restrict__ contains,
      int* __restrict__ winner, float* __restrict__ out) {
    __shared__ float vec[CAP * 65];          // 24.96 KB (also reused by transpose)
    __shared__ unsigned short smap[1024];    // 2 KB, 0xFFFF = empty
    __shared__ unsigned int   slist[1024];   // 4 KB: (p<<10) | (row<<9) | y
    __shared__ int cnt;

    cooperative_groups::grid_group grid = cooperative_groups::this_grid();
    int bx  = blockIdx.x;
    int tid = threadIdx.x;

    // ---- phase 0: winner fill ----
    ((int4*)winner)[bx * 256 + tid] = make_int4(-1, -1, -1, -1);
    grid.sync();

    // ---- phase 1: transposes (0..631)  ||  scatter (632..944) ----
    if (bx < T_TOTAL) {
        float* tl = vec;                     // reuse vec as transpose buffer
        int t = bx;
        const float* in; float* outp; int HW, tpb;
        if (t < T3_TILES)                    { in = c3; outp = c3t; HW = HW3; tpb = 120; }
        else if ((t -= T3_TILES) < T4_TILES) { in = c4; outp = c4t; HW = HW4; tpb = 30; }
        else { t -= T4_TILES;                  in = c5; outp = c5t; HW = HW5; tpb = 8; }
        int b  = t / tpb;
        int p0 = (t - b * tpb) * 64;
        int lane = tid & 63, wave = tid >> 6;
        const float* in_b  = in   + (size_t)b * NC * HW;
        float*       out_b = outp + (size_t)b * HW * NC;
        int p = p0 + lane;
        if (p < HW) {
            for (int ch = wave; ch < NC; ch += 4)      // coalesced 256B reads
                tl[ch * 65 + lane] = in_b[(size_t)ch * HW + p];
        }
        __syncthreads();
        for (int pp = wave; pp < 64; pp += 4) {        // coalesced 256B writes
            int pq = p0 + pp;
            if (pq < HW) out_b[(size_t)pq * NC + lane] = tl[lane * 65 + pp];
        }
    } else if (bx < T_TOTAL + SCAT_BLOCKS) {
        int idx = (bx - T_TOTAL) * 256 + tid;          // b*NP + p
        if (idx < NB * NP && contains[idx] > 0) {
            int b  = idx / NP;
            int p  = idx - b * NP;
            int cx = coors[idx * 3 + 1];
            int cy = coors[idx * 3 + 2];
            if ((unsigned)cx < XSZ && (unsigned)cy < YSZ)      // mode='drop'
                atomicMax(&winner[((size_t)b * XSZ + cx) * YSZ + cy], p);
        }
    }
    grid.sync();

    // ---- phase 2: fused sample + dense write ----
    int b  = bx >> 8;                        // 0..3
    int x0 = (bx & 255) << 1;                // even x; block owns x0, x0+1

    if (tid == 0) cnt = 0;
    __syncthreads();

    // A: scan 2 winner rows (1024 cells, flat f = row*512+y), assign slots
    const int4* wr = (const int4*)(winner + ((size_t)b * XSZ + x0) * YSZ);
    int4 r = wr[tid];                        // 4 consecutive flat cells
    {
        int f0 = tid * 4;
        int pv[4] = { r.x, r.y, r.z, r.w };
#pragma unroll
        for (int j = 0; j < 4; ++j) {
            unsigned short s = 0xFFFF;
            if (pv[j] >= 0) {
                int sl = atomicAdd(&cnt, 1);
                slist[sl] = ((unsigned)pv[j] << 10) | (unsigned)(f0 + j);
                s = (unsigned short)sl;
            }
            smap[f0 + j] = s;
        }
    }
    __syncthreads();
    int n  = cnt;
    int nB = min(n, CAP);

    // B: compute winning-cell channel vectors into LDS
    int wave = tid >> 6, lane = tid & 63;
    const float* i3b = c3t + (size_t)b * HW3 * NC;
    const float* i4b = c4t + (size_t)b * HW4 * NC;
    const float* i5b = c5t + (size_t)b * HW5 * NC;
    for (int s = wave; s < nB; s += 4) {
        unsigned pk = slist[s];
        int p = pk >> 10, f = pk & 1023;
        int xs = x0 + (f >> 9), y = f & 511;
        int idx = b * NP + p;
        float px = pnts[idx * 2], py = pnts[idx * 2 + 1];
        float fa = bilinT(i3b, H3, W3, px, py, lane);
        float fb = bilinT(i4b, H4, W4, px, py, lane);
        float fc = bilinT(i5b, H5, W5, px, py, lane);
        size_t dbase = (((size_t)b * 3) * XSZ + xs) * YSZ + y;
        float d0 = dyn[dbase];
        float d1 = dyn[dbase + (size_t)XSZ * YSZ];
        float d2 = dyn[dbase + (size_t)2 * XSZ * YSZ];
        vec[s * 65 + lane] = fa * d0 + fb * d1 + fc * d2;
    }
    __syncthreads();

    // C: exactly-once dense write; per channel the block writes 1024
    //    consecutive floats (4 KB contiguous), one f4 per thread
    int f0 = tid * 4;
    int s0 = smap[f0], s1 = smap[f0 + 1], s2 = smap[f0 + 2], s3 = smap[f0 + 3];
    bool h0 = s0 < CAP, h1 = s1 < CAP, h2 = s2 < CAP, h3 = s3 < CAP;
    size_t obase = (size_t)b * NC * HWO + (size_t)x0 * YSZ + f0;
    for (int c = 0; c < NC; ++c) {
        f4 v = (f4)(0.0f);
        if (h0) v.x = vec[s0 * 65 + c];
        if (h1) v.y = vec[s1 * 65 + c];
        if (h2) v.z = vec[s2 * 65 + c];
        if (h3) v.w = vec[s3 * 65 + c];
        *(f4*)(out + obase + (size_t)c * HWO) = v;
    }

    // D: overflow slots (practically never taken)
    if (n > CAP) {
        __syncthreads();                     // order after phase-C zeros
        for (int s = CAP + wave; s < n; s += 4) {
            unsigned pk = slist[s];
            int p = pk >> 10, f = pk & 1023;
            int xs = x0 + (f >> 9), y = f & 511;
            int idx = b * NP + p;
            float px = pnts[idx * 2], py = pnts[idx * 2 + 1];
            float fa = bilinT(i3b, H3, W3, px, py, lane);
            float fb = bilinT(i4b, H4, W4, px, py, lane);
            float fc = bilinT(i5b, H5, W5, px, py, lane);
            size_t dbase = (((size_t)b * 3) * XSZ + xs) * YSZ + y;
            float d0 = dyn[dbase];
            float d1 = dyn[dbase + (size_t)XSZ * YSZ];
            float d2 = dyn[dbase + (size_t)2 * XSZ * YSZ];
            out[(((size_t)b * NC + lane) * XSZ + xs) * YSZ + y] =
                fa * d0 + fb * d1 + fc * d2;
        }
    }
}

// ---------------------------------------------------------------------------
// Fallback path kernels (used only if cooperative launch unavailable or ws
// too small): scatter + zero-fill + scattered sample from original layout.
// ---------------------------------------------------------------------------
__global__ void __launch_bounds__(256)
k_scatter(const int* __restrict__ coors, const int* __restrict__ contains,
          int* __restrict__ winner) {
    int idx = blockIdx.x * blockDim.x + threadIdx.x;
    if (idx >= NB * NP) return;
    if (contains[idx] <= 0) return;
    int b  = idx / NP;
    int p  = idx - b * NP;
    int cx = coors[idx * 3 + 1];
    int cy = coors[idx * 3 + 2];
    if ((unsigned)cx >= XSZ || (unsigned)cy >= YSZ) return;
    atomicMax(&winner[((size_t)b * XSZ + cx) * YSZ + cy], p);
}

__global__ void __launch_bounds__(256)
k_samp_fb(const int* __restrict__ coors, const int* __restrict__ contains,
          const float* __restrict__ pnts, const int* __restrict__ winner,
          const float* __restrict__ i3, const float* __restrict__ i4,
          const float* __restrict__ i5, const float* __restrict__ dyn,
          float* __restrict__ out) {
    int nw   = gridDim.x << 2;
    int wv   = (blockIdx.x << 2) + (threadIdx.x >> 6);
    int lane = threadIdx.x & 63;
    for (int idx = wv; idx < NB * NP; idx += nw) {
        if (contains[idx] <= 0) continue;
        int b = idx / NP;
        int p = idx - b * NP;
        int cx = coors[idx * 3 + 1];
        int cy = coors[idx * 3 + 2];
        if ((unsigned)cx >= XSZ || (unsigned)cy >= YSZ) continue;
        if (winner[((size_t)b * XSZ + cx) * YSZ + cy] != p) continue;
        float px = pnts[idx * 2], py = pnts[idx * 2 + 1];
        float fa = bilinG(i3 + (size_t)b * NC * HW3, H3, W3, px, py, lane, HW3);
        float fb = bilinG(i4 + (size_t)b * NC * HW4, H4, W4, px, py, lane, HW4);
        float fc = bilinG(i5 + (size_t)b * NC * HW5, H5, W5, px, py, lane, HW5);
        size_t dbase = (((size_t)b * 3) * XSZ + cx) * YSZ + cy;
        float d0 = dyn[dbase];
        float d1 = dyn[dbase + (size_t)XSZ * YSZ];
        float d2 = dyn[dbase + (size_t)2 * XSZ * YSZ];
        out[(((size_t)b * NC + lane) * XSZ + cx) * YSZ + cy] = fa * d0 + fb * d1 + fc * d2;
    }
}

__global__ void k_zero4(float4* __restrict__ p, long n4) {
    long i = (long)blockIdx.x * blockDim.x + threadIdx.x;
    long stride = (long)gridDim.x * blockDim.x;
    for (; i < n4; i += stride) p[i] = make_float4(0.f, 0.f, 0.f, 0.f);
}

extern "C" void kernel_launch(void* const* d_in, const int* in_sizes, int n_in,
                              void* d_out, int out_size, void* d_ws, size_t ws_size,
                              hipStream_t stream) {
    const float* c3       = (const float*)d_in[0];
    const float* c4       = (const float*)d_in[1];
    const float* c5       = (const float*)d_in[2];
    const float* dyn      = (const float*)d_in[3];
    const float* pnts     = (const float*)d_in[4];
    const int*   coors    = (const int*)d_in[5];
    const int*   contains = (const int*)d_in[6];
    float* out = (float*)d_out;

    // workspace layout
    char* ws = (char*)d_ws;
    size_t off = 0;
    int* winner = (int*)(ws + off);   off += (size_t)NB * XSZ * YSZ * 4;   // 4 MiB
    float* c3t  = (float*)(ws + off); off += (size_t)NB * NC * HW3 * 4;    // 7.9 MB
    float* c4t  = (float*)(ws + off); off += (size_t)NB * NC * HW4 * 4;    // 2.0 MB
    float* c5t  = (float*)(ws + off); off += (size_t)NB * NC * HW5 * 4;    // 0.5 MB
    size_t t_need = off;                                                    // ~14.5 MB
    bool useT = (ws_size >= t_need);

    bool launched = false;
    if (useT) {
        void* args[12] = {
            (void*)&c3, (void*)&c4, (void*)&c5,
            (void*)&c3t, (void*)&c4t, (void*)&c5t,
            (void*)&dyn, (void*)&pnts, (void*)&coors, (void*)&contains,
            (void*)&winner, (void*)&out
        };
        hipError_t e = hipLaunchCooperativeKernel((void*)k_all, dim3(GRID2),
                                                  dim3(256), args, 0, stream);
        launched = (e == hipSuccess);
    }

    if (!launched) {
        // conservative fallback: fill + scatter + zero + scattered sample
        int npts = NB * NP;
        hipMemsetAsync(winner, 0xFF, (size_t)NB * XSZ * YSZ * 4, stream);
        k_scatter<<<(npts + 255) / 256, 256, 0, stream>>>(coors, contains, winner);
        long n4 = (long)out_size / 4;
        k_zero4<<<8192, 256, 0, stream>>>((float4*)out, n4);
        k_samp_fb<<<2048, 256, 0, stream>>>(coors, contains, pnts, winner,
                                            c3, c4, c5, dyn, out);
    }
}

// Round 11
// 74.641 us; speedup vs baseline: 3.3258x; 3.3258x over previous
//
#include <hip/hip_runtime.h>
#include <cstddef>

#define XSZ 512
#define YSZ 512
#define NB  4
#define NC  64
#define NP  20000
#define H3 48
#define W3 160
#define H4 24
#define W4 80
#define H5 12
#define W5 40
#define HW3 (H3*W3)
#define HW4 (H4*W4)
#define HW5 (H5*W5)
#define HWO (XSZ*YSZ)
#define SLOT_CAP 128     // winners/row: mean ~19.5, max ~45; overflow -> phase D

#define FILL_BLOCKS 256                    // 256 blk * 256 thr * 4 int4 = 4 MiB winner fill
#define T3_TILES (NB * ((HW3 + 63) / 64))  // 480
#define T4_TILES (NB * ((HW4 + 63) / 64))  // 120
#define T5_TILES (NB * ((HW5 + 63) / 64))  // 32

typedef float f4 __attribute__((ext_vector_type(4)));

// ---------------------------------------------------------------------------
// Fused init: winner <- -1 (int4 fill)  +  LDS-tiled transpose [B,C,H,W] ->
// [B,H,W,C] for all three images (reads AND writes coalesced).
// (Exact R6-winning version; cooperative variant regressed 3x -> reverted.)
// ---------------------------------------------------------------------------
__global__ void __launch_bounds__(256)
k_init(int4* __restrict__ winner4,
       const float* __restrict__ c3, const float* __restrict__ c4,
       const float* __restrict__ c5,
       float* __restrict__ c3t, float* __restrict__ c4t, float* __restrict__ c5t) {
    int blk = blockIdx.x;
    if (blk < FILL_BLOCKS) {
        int base = blk * 1024 + threadIdx.x;
        int4 m1 = make_int4(-1, -1, -1, -1);
        winner4[base      ] = m1;
        winner4[base + 256] = m1;
        winner4[base + 512] = m1;
        winner4[base + 768] = m1;
        return;
    }
    __shared__ float lds[NC * 65];
    int t = blk - FILL_BLOCKS;
    const float* in; float* outp; int HW, tpb;
    if (t < T3_TILES)                      { in = c3; outp = c3t; HW = HW3; tpb = 120; }
    else if ((t -= T3_TILES) < T4_TILES)   { in = c4; outp = c4t; HW = HW4; tpb = 30; }
    else { t -= T4_TILES;                    in = c5; outp = c5t; HW = HW5; tpb = 8; }
    int b  = t / tpb;
    int p0 = (t - b * tpb) * 64;
    int lane = threadIdx.x & 63, wave = threadIdx.x >> 6;
    const float* in_b  = in   + (size_t)b * NC * HW;
    float*       out_b = outp + (size_t)b * HW * NC;

    int p = p0 + lane;
    if (p < HW) {
        for (int ch = wave; ch < NC; ch += 4)          // coalesced 256B reads
            lds[ch * 65 + lane] = in_b[(size_t)ch * HW + p];
    }
    __syncthreads();
    for (int pp = wave; pp < 64; pp += 4) {            // coalesced 256B writes
        int pq = p0 + pp;
        if (pq < HW) out_b[(size_t)pq * NC + lane] = lds[lane * 65 + pp];
    }
}

// ---------------------------------------------------------------------------
// Scatter: winner[b][cx][cy] = max point-index p with contains>0
// (numpy fancy-assignment last-write-wins == max p)
// ---------------------------------------------------------------------------
__global__ void __launch_bounds__(256)
k_scatter(const int* __restrict__ coors, const int* __restrict__ contains,
          int* __restrict__ winner) {
    int idx = blockIdx.x * blockDim.x + threadIdx.x;   // b*NP + p
    if (idx >= NB * NP) return;
    if (contains[idx] <= 0) return;
    int b  = idx / NP;
    int p  = idx - b * NP;
    int cx = coors[idx * 3 + 1];
    int cy = coors[idx * 3 + 2];
    if ((unsigned)cx >= XSZ || (unsigned)cy >= YSZ) return;   // mode='drop'
    atomicMax(&winner[((size_t)b * XSZ + cx) * YSZ + cy], p);
}

// ---------------------------------------------------------------------------
// Bilinear, exact f32 replay of the reference arithmetic. Transposed [H,W,C]
// layout: per-tap wave read = 64 consecutive floats = one 256B segment.
// ---------------------------------------------------------------------------
__device__ __forceinline__ float bilinT(const float* __restrict__ img, int H, int W,
                                        float px, float py, int c) {
    float gx = px * 2.0f - 1.0f;
    float gy = py * 2.0f - 1.0f;
    float x = (gx + 1.0f) * 0.5f * (float)(W - 1);
    float y = (gy + 1.0f) * 0.5f * (float)(H - 1);
    float x0f = floorf(x), y0f = floorf(y);
    float wx1 = x - x0f,   wy1 = y - y0f;
    float wx0 = 1.0f - wx1, wy0 = 1.0f - wy1;
    int x0 = (int)x0f, y0 = (int)y0f;
    float acc = 0.0f;
#pragma unroll
    for (int dy = 0; dy < 2; ++dy) {
#pragma unroll
        for (int dx = 0; dx < 2; ++dx) {
            int xi = x0 + dx, yi = y0 + dy;
            bool valid = (xi >= 0) && (xi <= W - 1) && (yi >= 0) && (yi <= H - 1);
            int xc = min(max(xi, 0), W - 1);
            int yc = min(max(yi, 0), H - 1);
            float w = (dx ? wx1 : wx0) * (dy ? wy1 : wy0);
            float v = img[(size_t)(yc * W + xc) * NC + c];
            acc = fmaf(v, valid ? w : 0.0f, acc);
        }
    }
    return acc;
}

// generic-stride variant for the no-transpose fallback
__device__ __forceinline__ float bilinG(const float* __restrict__ img, int H, int W,
                                        float px, float py, int c, int sChan) {
    float gx = px * 2.0f - 1.0f;
    float gy = py * 2.0f - 1.0f;
    float x = (gx + 1.0f) * 0.5f * (float)(W - 1);
    float y = (gy + 1.0f) * 0.5f * (float)(H - 1);
    float x0f = floorf(x), y0f = floorf(y);
    float wx1 = x - x0f,   wy1 = y - y0f;
    float wx0 = 1.0f - wx1, wy0 = 1.0f - wy1;
    int x0 = (int)x0f, y0 = (int)y0f;
    float acc = 0.0f;
#pragma unroll
    for (int dy = 0; dy < 2; ++dy) {
#pragma unroll
        for (int dx = 0; dx < 2; ++dx) {
            int xi = x0 + dx, yi = y0 + dy;
            bool valid = (xi >= 0) && (xi <= W - 1) && (yi >= 0) && (yi <= H - 1);
            int xc = min(max(xi, 0), W - 1);
            int yc = min(max(yi, 0), W - 1 + (H - W));  // placeholder, not used
            yc = min(max(yi, 0), H - 1);
            float w = (dx ? wx1 : wx0) * (dy ? wy1 : wy0);
            float v = img[(size_t)(yc * W + xc) + (size_t)c * sChan];
            acc = fmaf(v, valid ? w : 0.0f, acc);
        }
    }
    return acc;
}

// ---------------------------------------------------------------------------
// Fused sample + dense writer. 512 THREADS (8 waves) per block; block owns
// one (b,x) output slab (64c x 512y, 128 KB). vs the 256-thread R6 winner,
// this halves both serial depths: phase B <=3 rounds/wave (was ~5), phase C
// 16 gather+store iterations/thread (was 32). LDS 39.3 KB -> 4 blocks/CU,
// 32 waves/CU (max occupancy).
// Phase A: scan winner row (1 cell/thread) -> slot list. Phase B: one wave
// per winning cell, 3 bilinears (lane=channel) into vec[slot][65].
// Phase C: exactly-once float4-coalesced dense write (4 channels per pass).
// Phase D: overflow cells (>SLOT_CAP; ~never) scattered stores.
// ---------------------------------------------------------------------------
__global__ void __launch_bounds__(512)
k_fused(const float* __restrict__ pnts, const int* __restrict__ winner,
        const float* __restrict__ i3t, const float* __restrict__ i4t,
        const float* __restrict__ i5t, const float* __restrict__ dyn,
        float* __restrict__ out) {
    __shared__ float vec[SLOT_CAP * 65];     // 33.3 KB
    __shared__ int smap[YSZ];                // 2 KB, -1 = empty
    __shared__ int slist[YSZ];
    __shared__ int ylist[YSZ];
    __shared__ int cnt;

    int bx = blockIdx.x;                 // b*512 + x
    int b = bx >> 9, x = bx & 511;
    int tid = threadIdx.x;
    if (tid == 0) cnt = 0;
    __syncthreads();

    // --- phase A: row scan, slot assignment (1 cell per thread) ---
    int pv = winner[((size_t)b * XSZ + x) * YSZ + tid];
    {
        int s = -1;
        if (pv >= 0) {
            s = atomicAdd(&cnt, 1);
            slist[s] = pv;
            ylist[s] = tid;
        }
        smap[tid] = s;
    }
    __syncthreads();
    int n = cnt;
    int nB = min(n, SLOT_CAP);

    // --- phase B: compute winning-cell channel vectors into LDS ---
    int wave = tid >> 6, lane = tid & 63;    // 8 waves
    const float* i3b = i3t + (size_t)b * HW3 * NC;
    const float* i4b = i4t + (size_t)b * HW4 * NC;
    const float* i5b = i5t + (size_t)b * HW5 * NC;
    for (int s = wave; s < nB; s += 8) {
        int p = slist[s], y = ylist[s];
        int idx = b * NP + p;
        float px = pnts[idx * 2], py = pnts[idx * 2 + 1];
        float fa = bilinT(i3b, H3, W3, px, py, lane);
        float fb = bilinT(i4b, H4, W4, px, py, lane);
        float fc = bilinT(i5b, H5, W5, px, py, lane);
        size_t dbase = (((size_t)b * 3) * XSZ + x) * YSZ + y;
        float d0 = dyn[dbase];
        float d1 = dyn[dbase + (size_t)XSZ * YSZ];
        float d2 = dyn[dbase + (size_t)2 * XSZ * YSZ];
        vec[s * 65 + lane] = fa * d0 + fb * d1 + fc * d2;
    }
    __syncthreads();

    // --- phase C: exactly-once coalesced dense write (4 channels/pass) ---
    int lane_c = tid >> 7;               // 0..3
    int t7 = tid & 127;
    int y4 = t7 << 2;
    int s0 = smap[y4], s1 = smap[y4 + 1], s2 = smap[y4 + 2], s3 = smap[y4 + 3];
    bool h0 = (unsigned)s0 < SLOT_CAP, h1 = (unsigned)s1 < SLOT_CAP;
    bool h2 = (unsigned)s2 < SLOT_CAP, h3 = (unsigned)s3 < SLOT_CAP;
    size_t obase = (size_t)b * NC * HWO + (size_t)x * YSZ + y4;
    for (int cb = 0; cb < NC; cb += 4) {
        int c = cb + lane_c;
        f4 v = (f4)(0.0f);
        if (h0) v.x = vec[s0 * 65 + c];
        if (h1) v.y = vec[s1 * 65 + c];
        if (h2) v.z = vec[s2 * 65 + c];
        if (h3) v.w = vec[s3 * 65 + c];
        *(f4*)(out + obase + (size_t)c * HWO) = v;
    }

    // --- phase D: overflow slots (practically never taken) ---
    if (n > SLOT_CAP) {
        __syncthreads();                 // order after phase-C zeros
        for (int s = SLOT_CAP + wave; s < n; s += 8) {
            int p = slist[s], y = ylist[s];
            int idx = b * NP + p;
            float px = pnts[idx * 2], py = pnts[idx * 2 + 1];
            float fa = bilinT(i3b, H3, W3, px, py, lane);
            float fb = bilinT(i4b, H4, W4, px, py, lane);
            float fc = bilinT(i5b, H5, W5, px, py, lane);
            size_t dbase = (((size_t)b * 3) * XSZ + x) * YSZ + y;
            float d0 = dyn[dbase];
            float d1 = dyn[dbase + (size_t)XSZ * YSZ];
            float d2 = dyn[dbase + (size_t)2 * XSZ * YSZ];
            out[(((size_t)b * NC + lane) * XSZ + x) * YSZ + y] =
                fa * d0 + fb * d1 + fc * d2;
        }
    }
}

// fallback: scattered direct store into pre-zeroed out, untransposed images
__global__ void __launch_bounds__(256)
k_samp_fb(const int* __restrict__ coors, const int* __restrict__ contains,
          const float* __restrict__ pnts, const int* __restrict__ winner,
          const float* __restrict__ i3, const float* __restrict__ i4,
          const float* __restrict__ i5, const float* __restrict__ dyn,
          float* __restrict__ out) {
    int nw   = gridDim.x << 2;
    int wv   = (blockIdx.x << 2) + (threadIdx.x >> 6);
    int lane = threadIdx.x & 63;
    for (int idx = wv; idx < NB * NP; idx += nw) {
        if (contains[idx] <= 0) continue;
        int b = idx / NP;
        int p = idx - b * NP;
        int cx = coors[idx * 3 + 1];
        int cy = coors[idx * 3 + 2];
        if ((unsigned)cx >= XSZ || (unsigned)cy >= YSZ) continue;
        if (winner[((size_t)b * XSZ + cx) * YSZ + cy] != p) continue;
        float px = pnts[idx * 2], py = pnts[idx * 2 + 1];
        float fa = bilinG(i3 + (size_t)b * NC * HW3, H3, W3, px, py, lane, HW3);
        float fb = bilinG(i4 + (size_t)b * NC * HW4, H4, W4, px, py, lane, HW4);
        float fc = bilinG(i5 + (size_t)b * NC * HW5, H5, W5, px, py, lane, HW5);
        size_t dbase = (((size_t)b * 3) * XSZ + cx) * YSZ + cy;
        float d0 = dyn[dbase];
        float d1 = dyn[dbase + (size_t)XSZ * YSZ];
        float d2 = dyn[dbase + (size_t)2 * XSZ * YSZ];
        out[(((size_t)b * NC + lane) * XSZ + cx) * YSZ + cy] = fa * d0 + fb * d1 + fc * d2;
    }
}

// fast zero-fill for fallback path
__global__ void k_zero4(float4* __restrict__ p, long n4) {
    long i = (long)blockIdx.x * blockDim.x + threadIdx.x;
    long stride = (long)gridDim.x * blockDim.x;
    for (; i < n4; i += stride) p[i] = make_float4(0.f, 0.f, 0.f, 0.f);
}

extern "C" void kernel_launch(void* const* d_in, const int* in_sizes, int n_in,
                              void* d_out, int out_size, void* d_ws, size_t ws_size,
                              hipStream_t stream) {
    const float* c3       = (const float*)d_in[0];
    const float* c4       = (const float*)d_in[1];
    const float* c5       = (const float*)d_in[2];
    const float* dyn      = (const float*)d_in[3];
    const float* pnts     = (const float*)d_in[4];
    const int*   coors    = (const int*)d_in[5];
    const int*   contains = (const int*)d_in[6];
    float* out = (float*)d_out;

    // workspace layout
    char* ws = (char*)d_ws;
    size_t off = 0;
    int* winner = (int*)(ws + off);   off += (size_t)NB * XSZ * YSZ * 4;   // 4 MiB
    float* c3t  = (float*)(ws + off); off += (size_t)NB * NC * HW3 * 4;    // 7.9 MB
    float* c4t  = (float*)(ws + off); off += (size_t)NB * NC * HW4 * 4;    // 2.0 MB
    float* c5t  = (float*)(ws + off); off += (size_t)NB * NC * HW5 * 4;    // 0.5 MB
    size_t t_need = off;                                                    // ~14.5 MB
    bool useT = (ws_size >= t_need);

    int npts = NB * NP;
    int init_blocks = useT ? (FILL_BLOCKS + T3_TILES + T4_TILES + T5_TILES)
                           : FILL_BLOCKS;
    k_init<<<init_blocks, 256, 0, stream>>>((int4*)winner, c3, c4, c5,
                                            c3t, c4t, c5t);
    k_scatter<<<(npts + 255) / 256, 256, 0, stream>>>(coors, contains, winner);

    if (useT) {
        // 3-dispatch main path: no output zero-fill, no intermediate buffer
        k_fused<<<NB * XSZ, 512, 0, stream>>>(pnts, winner, c3t, c4t, c5t,
                                              dyn, out);
    } else {
        long n4 = (long)out_size / 4;
        k_zero4<<<8192, 256, 0, stream>>>((float4*)out, n4);
        k_samp_fb<<<2048, 256, 0, stream>>>(coors, contains, pnts, winner,
                                            c3, c4, c5, dyn, out);
    }
}